// Round 1
// baseline (554.703 us; speedup 1.0000x reference)
//
#include <hip/hip_runtime.h>

typedef __attribute__((ext_vector_type(8))) short short8;
typedef __attribute__((ext_vector_type(4))) float f32x4;
typedef unsigned short ushort_t;
typedef unsigned int uint_t;

#define MFMA16(a, b, c) __builtin_amdgcn_mfma_f32_16x16x32_bf16((a), (b), (c), 0, 0, 0)

__device__ __forceinline__ ushort_t f2bf(float f) {
    union { float f; uint_t u; } c; c.f = f;
    uint_t u = c.u;
    uint_t r = (u + 0x7FFFu + ((u >> 16) & 1u)) >> 16;
    return (ushort_t)r;
}
__device__ __forceinline__ uint_t pack2(float a, float b) {
    return (uint_t)f2bf(a) | ((uint_t)f2bf(b) << 16);
}

// ---------------------------------------------------------------------------
// Kernel 1: DPB MLP -> dpb_vals[289]. One point per wave, lanes = 64 channels.
// ---------------------------------------------------------------------------
__device__ __forceinline__ float wredsum(float v) {
    #pragma unroll
    for (int m = 1; m < 64; m <<= 1) v += __shfl_xor(v, m);
    return v;
}

__global__ void dpb_vals_kernel(const float* __restrict__ w1, const float* __restrict__ b1,
                                const float* __restrict__ g1, const float* __restrict__ be1,
                                const float* __restrict__ w2, const float* __restrict__ b2,
                                const float* __restrict__ g2, const float* __restrict__ be2,
                                const float* __restrict__ w3, const float* __restrict__ b3,
                                const float* __restrict__ g3, const float* __restrict__ be3,
                                const float* __restrict__ w4, const float* __restrict__ b4,
                                float* __restrict__ valsg) {
    int wv = threadIdx.x >> 6, j = threadIdx.x & 63;
    int pt = blockIdx.x * 8 + wv;
    if (pt >= 289) return;
    float ri = (float)(pt / 17 - 8), rj = (float)(pt % 17 - 8);

    // layer 1
    float t = ri * w1[2 * j] + rj * w1[2 * j + 1] + b1[j];
    float mu = wredsum(t) * (1.f / 64.f);
    float d = t - mu;
    float var = wredsum(d * d) * (1.f / 64.f);
    float h = fmaxf(0.f, d * rsqrtf(var + 1e-5f) * g1[j] + be1[j]);

    // layer 2
    float a = b2[j];
    for (int k = 0; k < 64; ++k) a += __shfl(h, k) * w2[j * 64 + k];
    mu = wredsum(a) * (1.f / 64.f);
    d = a - mu;
    var = wredsum(d * d) * (1.f / 64.f);
    h = fmaxf(0.f, d * rsqrtf(var + 1e-5f) * g2[j] + be2[j]);

    // layer 3
    a = b3[j];
    for (int k = 0; k < 64; ++k) a += __shfl(h, k) * w3[j * 64 + k];
    mu = wredsum(a) * (1.f / 64.f);
    d = a - mu;
    var = wredsum(d * d) * (1.f / 64.f);
    h = fmaxf(0.f, d * rsqrtf(var + 1e-5f) * g3[j] + be3[j]);

    // layer 4
    float v = wredsum(h * w4[j]) + b4[0];
    if (j == 0) valsg[pt] = v;
}

// ---------------------------------------------------------------------------
// Kernel 2: convert weights to bf16 + expand bias table [64][64]
// ---------------------------------------------------------------------------
__global__ void cvt_kernel(const float* __restrict__ wqkv, const float* __restrict__ wout,
                           const float* __restrict__ valsg,
                           ushort_t* __restrict__ wbf, float* __restrict__ biasg) {
    int i = blockIdx.x * 512 + threadIdx.x;   // grid 520 -> 266240 threads
    if (i < 196608) {
        wbf[i] = f2bf(wqkv[i]);
    } else if (i < 262144) {
        wbf[i] = f2bf(wout[i - 196608]);
    } else {
        int idx = i - 262144;                 // < 4096
        int r = idx >> 6, c = idx & 63;
        int p = ((r >> 3) - (c >> 3) + 7) * 15 + ((r & 7) - (c & 7) + 7);
        biasg[idx] = valsg[p];
    }
}

// ---------------------------------------------------------------------------
// Main fused kernel: one workgroup (512 thr, 8 waves) per 8x8 window.
// LDS map (bytes):
//   [0, 118784)   : head buffers, 8 x 14848  { Q[64][40]bf16 pad80B | K same | V[32][72]bf16 pad144B }
//                   (P[64][72]bf16 overlays Q+K after sim)
//                   Xs f32[256][64] (65536B) overlays this region in phases 1-2
//   [118784, +32768) : XN/OT bf16 [64 rows][256] 512B rows, XOR-swizzled
//   [151552, +4096)  : red[2][8][64] f32
//   [155648, +512)   : mu[64], rstd[64]
// ---------------------------------------------------------------------------
#define LDS_BYTES 156160
#define SCALE_Q 0.17677669529663687f

__global__ __launch_bounds__(512) void win_attn(
    const float* __restrict__ x, const float* __restrict__ gamw, const float* __restrict__ betw,
    const ushort_t* __restrict__ wqkv, const ushort_t* __restrict__ wout,
    const float* __restrict__ boutp, const float* __restrict__ biasg,
    float* __restrict__ outp) {
    extern __shared__ char smem[];
    const int tid = threadIdx.x;
    const int wid = blockIdx.x;
    const int bb = wid >> 10, rem = wid & 1023, wh = rem >> 5, ww = rem & 31;
    const int xoff = bb * 16777216 + wh * 2048 + ww * 8;
    const float* xb = x + xoff;

    float* Xs = (float*)smem;
    char* XNb = smem + 118784;
    float* red = (float*)(smem + 151552);
    float* muv = (float*)(smem + 155648);

    // ---- phase 1: load window -> Xs[d][n] ----
    #pragma unroll
    for (int it = 0; it < 8; ++it) {
        int idx = it * 512 + tid;
        int d = idx >> 4, p4 = idx & 15;
        int py = p4 >> 1, c4 = (p4 & 1) << 2;
        float4 v = *(const float4*)(xb + d * 65536 + py * 256 + c4);
        *(float4*)&Xs[d * 64 + py * 8 + c4] = v;
    }
    __syncthreads();

    // ---- phase 2: channel-LN stats ----
    {
        int n = tid & 63, dq = tid >> 6;
        float s = 0.f, s2 = 0.f;
        #pragma unroll
        for (int i2 = 0; i2 < 32; ++i2) {
            float v = Xs[(dq * 32 + i2) * 64 + n];
            s += v; s2 += v * v;
        }
        red[dq * 64 + n] = s;
        red[512 + dq * 64 + n] = s2;
    }
    __syncthreads();
    if (tid < 64) {
        float s = 0.f, s2 = 0.f;
        #pragma unroll
        for (int q = 0; q < 8; ++q) { s += red[q * 64 + tid]; s2 += red[512 + q * 64 + tid]; }
        float mu = s * 0.00390625f;
        float var = s2 * 0.00390625f - mu * mu;
        muv[tid] = mu;
        muv[64 + tid] = rsqrtf(var + 1e-5f);
    }
    __syncthreads();

    // ---- normalize -> XN[n][d] bf16 (swizzled) ----
    {
        int n = tid & 63, dc = tid >> 6;
        float mu = muv[n], rs = muv[64 + n];
        #pragma unroll
        for (int jj = 0; jj < 4; ++jj) {
            int d0 = dc * 32 + jj * 8;
            uint_t p0, p1, p2, p3;
            {
                float a0 = (Xs[(d0 + 0) * 64 + n] - mu) * rs * gamw[d0 + 0] + betw[d0 + 0];
                float a1 = (Xs[(d0 + 1) * 64 + n] - mu) * rs * gamw[d0 + 1] + betw[d0 + 1];
                float a2 = (Xs[(d0 + 2) * 64 + n] - mu) * rs * gamw[d0 + 2] + betw[d0 + 2];
                float a3 = (Xs[(d0 + 3) * 64 + n] - mu) * rs * gamw[d0 + 3] + betw[d0 + 3];
                float a4 = (Xs[(d0 + 4) * 64 + n] - mu) * rs * gamw[d0 + 4] + betw[d0 + 4];
                float a5 = (Xs[(d0 + 5) * 64 + n] - mu) * rs * gamw[d0 + 5] + betw[d0 + 5];
                float a6 = (Xs[(d0 + 6) * 64 + n] - mu) * rs * gamw[d0 + 6] + betw[d0 + 6];
                float a7 = (Xs[(d0 + 7) * 64 + n] - mu) * rs * gamw[d0 + 7] + betw[d0 + 7];
                p0 = pack2(a0, a1); p1 = pack2(a2, a3); p2 = pack2(a4, a5); p3 = pack2(a6, a7);
            }
            int bo = (n << 9) + (d0 << 1);
            bo ^= ((bo >> 9) & 7) << 4;
            uint4 q4; q4.x = p0; q4.y = p1; q4.z = p2; q4.w = p3;
            *(uint4*)(XNb + bo) = q4;
        }
    }
    __syncthreads();

    const int wv = tid >> 6, l = tid & 63, g = l >> 4, m15 = l & 15;

    // ---- phase 3: QKV GEMM (wave wv owns output rows [wv*96, wv*96+96)) ----
    {
        f32x4 acc[6][4] = {};
        for (int kt = 0; kt < 8; ++kt) {
            short8 bfr[4];
            #pragma unroll
            for (int nt = 0; nt < 4; ++nt) {
                int bo = ((nt * 16 + m15) << 9) + kt * 64 + g * 16;
                bo ^= ((bo >> 9) & 7) << 4;
                bfr[nt] = *(const short8*)(XNb + bo);
            }
            #pragma unroll
            for (int mt = 0; mt < 6; ++mt) {
                int row = wv * 96 + mt * 16 + m15;
                short8 afr = *(const short8*)(wqkv + row * 256 + kt * 32 + g * 8);
                #pragma unroll
                for (int nt = 0; nt < 4; ++nt)
                    acc[mt][nt] = MFMA16(afr, bfr[nt], acc[mt][nt]);
            }
        }
        // scatter to per-head Q/K/V LDS tiles
        #pragma unroll
        for (int mt = 0; mt < 6; ++mt) {
            int rowb = wv * 96 + mt * 16 + g * 4;
            int sec = rowb >> 8;
            int h = (rowb >> 5) & 7;
            int dh = rowb & 31;
            char* base = smem + h * 14848 + (sec == 2 ? 10240 : sec * 5120);
            #pragma unroll
            for (int nt = 0; nt < 4; ++nt) {
                f32x4 a = acc[mt][nt];
                if (sec == 0) { a[0] *= SCALE_Q; a[1] *= SCALE_Q; a[2] *= SCALE_Q; a[3] *= SCALE_Q; }
                int n = nt * 16 + m15;
                if (sec < 2) {
                    uint2 pv; pv.x = pack2(a[0], a[1]); pv.y = pack2(a[2], a[3]);
                    *(uint2*)(base + n * 80 + dh * 2) = pv;   // Q/K: [n][dh], stride 80B
                } else {
                    #pragma unroll
                    for (int e = 0; e < 4; ++e)
                        *(ushort_t*)(base + (dh + e) * 144 + n * 2) = f2bf(a[e]);  // V: [dh][j]
                }
            }
        }
    }
    __syncthreads();

    // ---- phase 4: attention, wave wv = head wv ----
    {
        char* Qb = smem + wv * 14848;
        char* Kb = Qb + 5120;
        char* Vb = Qb + 10240;
        char* Pb = Qb;   // P overlays Q+K

        short8 qa[4], kf[4];
        #pragma unroll
        for (int t4 = 0; t4 < 4; ++t4) {
            qa[t4] = *(const short8*)(Qb + (t4 * 16 + m15) * 80 + g * 16);
            kf[t4] = *(const short8*)(Kb + (t4 * 16 + m15) * 80 + g * 16);
        }
        f32x4 s[4][4];
        #pragma unroll
        for (int mt = 0; mt < 4; ++mt)
            #pragma unroll
            for (int nt = 0; nt < 4; ++nt) {
                f32x4 z = {};
                s[mt][nt] = MFMA16(qa[mt], kf[nt], z);
            }
        // bias + softmax over j (rows i distributed over lanes&15 x 4 regs)
        #pragma unroll
        for (int mt = 0; mt < 4; ++mt) {
            #pragma unroll
            for (int e = 0; e < 4; ++e) {
                int i = mt * 16 + g * 4 + e;
                const float* brow = biasg + i * 64 + m15;
                s[mt][0][e] += brow[0];
                s[mt][1][e] += brow[16];
                s[mt][2][e] += brow[32];
                s[mt][3][e] += brow[48];
                float mx = fmaxf(fmaxf(s[mt][0][e], s[mt][1][e]), fmaxf(s[mt][2][e], s[mt][3][e]));
                for (int xm = 1; xm < 16; xm <<= 1) mx = fmaxf(mx, __shfl_xor(mx, xm));
                float sum = 0.f;
                #pragma unroll
                for (int nt = 0; nt < 4; ++nt) {
                    float p = __expf(s[mt][nt][e] - mx);
                    s[mt][nt][e] = p; sum += p;
                }
                for (int xm = 1; xm < 16; xm <<= 1) sum += __shfl_xor(sum, xm);
                float inv = 1.f / sum;
                #pragma unroll
                for (int nt = 0; nt < 4; ++nt) s[mt][nt][e] *= inv;
            }
        }
        // write P[i][j] bf16 (stride 144B)
        #pragma unroll
        for (int mt = 0; mt < 4; ++mt)
            #pragma unroll
            for (int nt = 0; nt < 4; ++nt)
                #pragma unroll
                for (int e = 0; e < 4; ++e) {
                    int i = mt * 16 + g * 4 + e, j = nt * 16 + m15;
                    *(ushort_t*)(Pb + i * 144 + j * 2) = f2bf(s[mt][nt][e]);
                }
        // PV (swapped): D'[d][i] = sum_j V[d][j] * P[i][j]
        f32x4 o2[2][4] = {};
        #pragma unroll
        for (int ks = 0; ks < 2; ++ks) {
            short8 pb[4];
            #pragma unroll
            for (int nt = 0; nt < 4; ++nt)
                pb[nt] = *(const short8*)(Pb + (nt * 16 + m15) * 144 + ks * 64 + g * 16);
            #pragma unroll
            for (int mt2 = 0; mt2 < 2; ++mt2) {
                short8 va = *(const short8*)(Vb + (mt2 * 16 + m15) * 144 + ks * 64 + g * 16);
                #pragma unroll
                for (int nt = 0; nt < 4; ++nt)
                    o2[mt2][nt] = MFMA16(va, pb[nt], o2[mt2][nt]);
            }
        }
        // write OT[i][o=h*32+d] bf16 into XN buffer (swizzled)
        #pragma unroll
        for (int mt2 = 0; mt2 < 2; ++mt2)
            #pragma unroll
            for (int nt = 0; nt < 4; ++nt) {
                int i = nt * 16 + m15;
                int dd = wv * 32 + mt2 * 16 + g * 4;
                int bo = (i << 9) + (dd << 1);
                bo ^= ((bo >> 9) & 7) << 4;
                uint2 pv;
                pv.x = pack2(o2[mt2][nt][0], o2[mt2][nt][1]);
                pv.y = pack2(o2[mt2][nt][2], o2[mt2][nt][3]);
                *(uint2*)(XNb + bo) = pv;
            }
    }
    __syncthreads();

    // ---- phase 5: out projection + store ----
    {
        f32x4 po[2][4] = {};
        for (int kt = 0; kt < 8; ++kt) {
            short8 bfr[4];
            #pragma unroll
            for (int nt = 0; nt < 4; ++nt) {
                int bo = ((nt * 16 + m15) << 9) + kt * 64 + g * 16;
                bo ^= ((bo >> 9) & 7) << 4;
                bfr[nt] = *(const short8*)(XNb + bo);
            }
            #pragma unroll
            for (int mt = 0; mt < 2; ++mt) {
                int row = wv * 32 + mt * 16 + m15;
                short8 afr = *(const short8*)(wout + row * 256 + kt * 32 + g * 8);
                #pragma unroll
                for (int nt = 0; nt < 4; ++nt)
                    po[mt][nt] = MFMA16(afr, bfr[nt], po[mt][nt]);
            }
        }
        float* ob = outp + xoff;
        #pragma unroll
        for (int mt = 0; mt < 2; ++mt) {
            int o0 = wv * 32 + mt * 16 + g * 4;
            float bo0 = boutp[o0], bo1 = boutp[o0 + 1], bo2 = boutp[o0 + 2], bo3 = boutp[o0 + 3];
            #pragma unroll
            for (int nt = 0; nt < 4; ++nt) {
                int i = nt * 16 + m15;
                int pix = (i >> 3) * 256 + (i & 7);
                ob[(o0 + 0) * 65536 + pix] = po[mt][nt][0] + bo0;
                ob[(o0 + 1) * 65536 + pix] = po[mt][nt][1] + bo1;
                ob[(o0 + 2) * 65536 + pix] = po[mt][nt][2] + bo2;
                ob[(o0 + 3) * 65536 + pix] = po[mt][nt][3] + bo3;
            }
        }
    }
}

// ---------------------------------------------------------------------------
extern "C" void kernel_launch(void* const* d_in, const int* in_sizes, int n_in,
                              void* d_out, int out_size, void* d_ws, size_t ws_size,
                              hipStream_t stream) {
    const float* x     = (const float*)d_in[0];
    const float* g     = (const float*)d_in[1];
    const float* b     = (const float*)d_in[2];
    const float* w_qkv = (const float*)d_in[3];
    const float* w_out = (const float*)d_in[4];
    const float* b_out = (const float*)d_in[5];
    const float* dw1 = (const float*)d_in[6],  *db1 = (const float*)d_in[7];
    const float* dg1 = (const float*)d_in[8],  *dbe1 = (const float*)d_in[9];
    const float* dw2 = (const float*)d_in[10], *db2 = (const float*)d_in[11];
    const float* dg2 = (const float*)d_in[12], *dbe2 = (const float*)d_in[13];
    const float* dw3 = (const float*)d_in[14], *db3 = (const float*)d_in[15];
    const float* dg3 = (const float*)d_in[16], *dbe3 = (const float*)d_in[17];
    const float* dw4 = (const float*)d_in[18], *db4 = (const float*)d_in[19];

    ushort_t* wbf   = (ushort_t*)d_ws;                         // 262144 bf16 = 524288 B
    float*    biasg = (float*)((char*)d_ws + 524288);          // 4096 f32   = 16384 B
    float*    valsg = (float*)((char*)d_ws + 540672);          // 289 f32

    hipLaunchKernelGGL(dpb_vals_kernel, dim3(37), dim3(512), 0, stream,
                       dw1, db1, dg1, dbe1, dw2, db2, dg2, dbe2,
                       dw3, db3, dg3, dbe3, dw4, db4, valsg);
    hipLaunchKernelGGL(cvt_kernel, dim3(520), dim3(512), 0, stream,
                       w_qkv, w_out, valsg, wbf, biasg);

    (void)hipFuncSetAttribute((const void*)win_attn,
                              hipFuncAttributeMaxDynamicSharedMemorySize, LDS_BYTES);
    hipLaunchKernelGGL(win_attn, dim3(2048), dim3(512), LDS_BYTES, stream,
                       x, g, b, wbf, wbf + 196608, b_out, biasg, (float*)d_out);
}